// Round 13
// baseline (926.969 us; speedup 1.0000x reference)
//
#include <hip/hip_runtime.h>
#include <hip/hip_cooperative_groups.h>

namespace cg = cooperative_groups;

#define N_NODES 10000
#define N_EDGES 160000
#define NUM_FEAT 14
#define DIM 64
#define HID 128
#define LAYERS 28

#define NPB 20
#define NLB (N_NODES / NPB)   // 500 (fallback split grid)
#define TPB 640               // 10 waves
#define CBLK 250              // coop grid: 1 block/CU guaranteed (R6-proven size)
#define TILEB 5000            // tile B node offset

// async global->LDS, 16B/lane: gsrc per-lane (base + lane*4 floats), lds_base
// wave-uniform; HW writes lds_base + lane*16.
__device__ __forceinline__ void stage16(const float* gsrc, float* lds_base) {
  __builtin_amdgcn_global_load_lds(
      (const __attribute__((address_space(1))) void*)gsrc,
      (__attribute__((address_space(3))) void*)lds_base, 16, 0, 0);
}

// ---------------- CSR build (prologue) ----------------

__global__ __launch_bounds__(256) void k_hist(const int* __restrict__ dst, int* __restrict__ cur) {
  int e = blockIdx.x * 256 + threadIdx.x;
  if (e < N_EDGES) atomicAdd(&cur[dst[e]], 1);
}

__global__ __launch_bounds__(256) void k_scan(int* __restrict__ cur, int* __restrict__ off) {
  __shared__ int part[256];
  int t = threadIdx.x;
  const int CH = 40;
  int base = t * CH;
  int s = 0;
  for (int i = 0; i < CH; i++) {
    int idx = base + i;
    if (idx < N_NODES) s += cur[idx];
  }
  part[t] = s;
  __syncthreads();
  for (int ofs = 1; ofs < 256; ofs <<= 1) {
    int tmp = (t >= ofs) ? part[t - ofs] : 0;
    __syncthreads();
    part[t] += tmp;
    __syncthreads();
  }
  int run = part[t] - s;
  for (int i = 0; i < CH; i++) {
    int idx = base + i;
    if (idx < N_NODES) {
      int d = cur[idx];
      off[idx] = run;
      cur[idx] = run;
      run += d;
    }
  }
  if (t == 255) off[N_NODES] = part[255];
}

__global__ __launch_bounds__(256) void k_scatter(const int* __restrict__ dst, int* __restrict__ cur,
                                                 int* __restrict__ eids) {
  int e = blockIdx.x * 256 + threadIdx.x;
  if (e < N_EDGES) {
    int p = atomicAdd(&cur[dst[e]], 1);
    eids[p] = e;
  }
}

// wave-per-node bitonic sort by edge id, then gather src and write the
// precomputed edge embedding ea_s[slot][f] = b_edge[f] + eattr[e]@W_edge[:,f].
__global__ __launch_bounds__(256) void k_sortgather(
    const int* __restrict__ off, const int* __restrict__ eids,
    const int* __restrict__ src, const float4* __restrict__ eattr,
    const float* __restrict__ W_edge, const float* __restrict__ b_edge,
    int* __restrict__ src_s, float4* __restrict__ eattr_s, float* __restrict__ ea_s) {
  int node = blockIdx.x * 4 + (threadIdx.x >> 6);
  int lane = threadIdx.x & 63;
  if (node >= N_NODES) return;
  float we0 = W_edge[lane], we1 = W_edge[64 + lane], we2 = W_edge[128 + lane],
        we3 = W_edge[192 + lane];
  float be = b_edge[lane];
  int a = off[node];
  int d = off[node + 1] - a;
  if (d <= 64) {
    int key = (lane < d) ? eids[a + lane] : 0x7fffffff;
#pragma unroll
    for (int k = 2; k <= 64; k <<= 1) {
      for (int j = k >> 1; j > 0; j >>= 1) {
        int p = __shfl_xor(key, j);
        bool dirUp = ((lane & k) == 0);
        bool isLower = ((lane & j) == 0);
        key = ((isLower == dirUp) ? min(key, p) : max(key, p));
      }
    }
    float4 ev = make_float4(0.f, 0.f, 0.f, 0.f);
    if (lane < d) {
      src_s[a + lane] = src[key];
      ev = eattr[key];
    }
    for (int j = 0; j < d; j++) {
      float ex = __shfl(ev.x, j), ey = __shfl(ev.y, j),
            ez = __shfl(ev.z, j), ew = __shfl(ev.w, j);
      ea_s[(size_t)(a + j) * 64 + lane] =
          be + ex * we0 + ey * we1 + ez * we2 + ew * we3;
    }
  } else {
    for (int i = lane; i < d; i += 64) {
      int e = eids[a + i];
      int r = 0;
      for (int j = 0; j < d; j++) r += (eids[a + j] < e) ? 1 : 0;
      src_s[a + r] = src[e];
      eattr_s[a + r] = eattr[e];
    }
    for (int j = 0; j < d; j++) {
      float4 e4 = eattr_s[a + j];
      ea_s[(size_t)(a + j) * 64 + lane] =
          be + e4.x * we0 + e4.y * we1 + e4.z * we2 + e4.w * we3;
    }
  }
}

// ---------------- node encoder (fallback path) ----------------

__global__ __launch_bounds__(256) void k_enc(const float* __restrict__ x, const float* __restrict__ Wn,
                                             const float* __restrict__ bn, float* __restrict__ hc,
                                             float* __restrict__ u) {
  int gid = blockIdx.x * 256 + threadIdx.x;
  if (gid >= N_NODES * DIM) return;
  int n = gid >> 6, j = gid & 63;
  float acc = bn[j];
#pragma unroll
  for (int k = 0; k < NUM_FEAT; k++) acc += x[n * NUM_FEAT + k] * Wn[k * DIM + j];
  hc[gid] = acc;
  u[gid] = acc;
}

// ---------------- device helpers (coop kernel phases) ----------------

// per-node edge aggregation (batch-8, max-free softmax) -> h value for this lane
__device__ __forceinline__ float edge_node(
    int gn, const float* __restrict__ uin, const float* __restrict__ ea_s,
    const int* __restrict__ src_s, const int* __restrict__ off,
    int lane, float tv) {
  int a = off[gn], d = off[gn + 1] - a;  // scalar (gn wave-uniform)
  float un = uin[(gn << 6) + lane];
  float s0 = 0.f, s1 = 0.f, ac0 = 0.f, ac1 = 0.f;
  int i = 0;
  for (; i + 8 <= d; i += 8) {
    float uv[8], ev[8];
#pragma unroll
    for (int j = 0; j < 8; j++) {
      int sn = src_s[a + i + j];                      // s_load
      uv[j] = uin[(sn << 6) + lane];                  // sgpr-base gather
      ev[j] = ea_s[(size_t)(a + i + j) * 64 + lane];  // coalesced stream
    }
#pragma unroll
    for (int j = 0; j < 8; j++) {
      float msg = fmaxf(uv[j] + ev[j], 0.f) + 1e-7f;
      float e = __expf(msg * tv);
      if (j & 1) { s1 += e; ac1 = fmaf(e, msg, ac1); }
      else       { s0 += e; ac0 = fmaf(e, msg, ac0); }
    }
  }
  for (; i < d; i++) {
    int sn = src_s[a + i];
    float msg = fmaxf(uin[(sn << 6) + lane] + ea_s[(size_t)(a + i) * 64 + lane],
                      0.f) + 1e-7f;
    float e = __expf(msg * tv);
    s0 += e;
    ac0 = fmaf(e, msg, ac0);
  }
  return (ac0 + ac1) / (s0 + s1 + 1e-16f) + un;
}

// ---------------- persistent cooperative kernel: enc + 28 layers + final ----------------
// 250 blocks x 640 threads (10 waves) -- 1 block/CU co-residency (R6-proven coop
// size; R11/R12 showed 500-block 2-per-CU coop is rejected). Each block handles
// TWO 20-node tiles per layer (A: bid*20, B: 5000+bid*20); wave owns 2 nodes per
// tile end-to-end, residual hc in 4 registers/thread for all 28 layers. W1/W2
// staged once per layer serve both tiles. One __syncthreads per layer (sHZ is
// wave-private: hA [0..128), hB [128..256), z [256..512)).

__global__ __launch_bounds__(TPB, 5) void k_all(
    const float* __restrict__ x,
    const float* __restrict__ W_node, const float* __restrict__ b_node,
    const float* __restrict__ t,
    const float* __restrict__ W1a, const float* __restrict__ b1a,
    const float* __restrict__ g1a, const float* __restrict__ be1a,
    const float* __restrict__ W2a, const float* __restrict__ b2a,
    const float* __restrict__ ln_g, const float* __restrict__ ln_b,
    const float* __restrict__ W_out, const float* __restrict__ b_out,
    float* __restrict__ out,
    const float* __restrict__ ea_s, const int* __restrict__ src_s,
    const int* __restrict__ off,
    float* uA, float* uB) {
  cg::grid_group grid = cg::this_grid();

  __shared__ float sW1[64 * 128];   // 32KB [k][j]
  __shared__ float sW2[128 * 64];   // 32KB [k][i]
  __shared__ float sHZ[10][512];    // 20KB: hA [0..128), hB [128..256), z [256..512)

  const int tid = threadIdx.x;
  const int lane = tid & 63;
  const int wv = tid >> 6;  // 0..9
  const int gnA0 = __builtin_amdgcn_readfirstlane(blockIdx.x * NPB + wv * 2);
  const int gnA1 = gnA0 + 1;
  const int gnB0 = gnA0 + TILEB;
  const int gnB1 = gnB0 + 1;

  // ---- node encoder for own 4 nodes ----
  {
    float wn[NUM_FEAT];
#pragma unroll
    for (int f = 0; f < NUM_FEAT; f++) wn[f] = W_node[f * 64 + lane];
    float bn = b_node[lane];
    float a0 = bn, a1 = bn, b0 = bn, b1v = bn;
#pragma unroll
    for (int f = 0; f < NUM_FEAT; f++) {
      a0 = fmaf(x[gnA0 * NUM_FEAT + f], wn[f], a0);
      a1 = fmaf(x[gnA1 * NUM_FEAT + f], wn[f], a1);
      b0 = fmaf(x[gnB0 * NUM_FEAT + f], wn[f], b0);
      b1v = fmaf(x[gnB1 * NUM_FEAT + f], wn[f], b1v);
    }
    uA[(gnA0 << 6) + lane] = a0;
    uA[(gnA1 << 6) + lane] = a1;
    uA[(gnB0 << 6) + lane] = b0;
    uA[(gnB1 << 6) + lane] = b1v;
  }
  grid.sync();  // enc visible device-wide

  float hcA0 = 0.f, hcA1 = 0.f, hcB0 = 0.f, hcB1 = 0.f;  // residuals in registers

  for (int l = 0; l < LAYERS; l++) {
    const float* uin = (l & 1) ? uB : uA;
    float* uout = (l & 1) ? uA : uB;
    const float* W1 = W1a + (size_t)l * 64 * 128;
    const float* W2 = W2a + (size_t)l * 128 * 64;
    const float* b1 = b1a + (size_t)l * 128;
    const float* g1 = g1a + (size_t)l * 128;
    const float* be1 = be1a + (size_t)l * 128;
    const float* b2 = b2a + (size_t)l * 64;

    // ---- stage weights (fire-and-forget; drained by the barrier) ----
    for (int c = wv; c < 32; c += 10) {
      stage16(W1 + c * 256 + lane * 4, sW1 + c * 256);
      stage16(W2 + c * 256 + lane * 4, sW2 + c * 256);
    }

    // ---- edge aggregation: both tiles (staging latency hides under 2x work) ----
    {
      float tv = t[l];
      float hA0 = edge_node(gnA0, uin, ea_s, src_s, off, lane, tv);
      float hA1 = edge_node(gnA1, uin, ea_s, src_s, off, lane, tv);
      *((float2*)&sHZ[wv][lane * 2]) = make_float2(hA0, hA1);
      float hB0 = edge_node(gnB0, uin, ea_s, src_s, off, lane, tv);
      float hB1 = edge_node(gnB1, uin, ea_s, src_s, off, lane, tv);
      *((float2*)&sHZ[wv][128 + lane * 2]) = make_float2(hB0, hB1);
    }
    __syncthreads();  // drains global_load_lds (weights ready); sHZ wave-private

    // ---- MLP for tile A then tile B (z region reused, same-wave ordered) ----
#pragma unroll
    for (int tb = 0; tb < 2; tb++) {
      const int hbase = tb * 128;
      float* hcp0 = tb ? &hcB0 : &hcA0;
      float* hcp1 = tb ? &hcB1 : &hcA1;
      const int g0 = tb ? gnB0 : gnA0;
      const int g1i = tb ? gnB1 : gnA1;

      // GEMM1: cols j0=2*lane, j0+1; 2 nodes
      int j0 = 2 * lane;
      float2 b1p = *((const float2*)&b1[j0]);
      float a00 = b1p.x, a01 = b1p.y, a10 = b1p.x, a11 = b1p.y;
#pragma unroll 8
      for (int k = 0; k < 64; k++) {
        float2 hp = *((float2*)&sHZ[wv][hbase + k * 2]);
        float2 wp = *((float2*)&sW1[k * 128 + j0]);
        a00 += hp.x * wp.x; a01 += hp.x * wp.y;
        a10 += hp.y * wp.x; a11 += hp.y * wp.y;
      }

      // LN1 (over 128) via shfl; z -> sHZ[256..512)
      {
        float2 gv = *((const float2*)&g1[j0]);
        float2 bev = *((const float2*)&be1[j0]);
        float s0 = a00 + a01, q0 = a00 * a00 + a01 * a01;
        float s1 = a10 + a11, q1 = a10 * a10 + a11 * a11;
#pragma unroll
        for (int o = 32; o; o >>= 1) {
          s0 += __shfl_xor(s0, o); q0 += __shfl_xor(q0, o);
          s1 += __shfl_xor(s1, o); q1 += __shfl_xor(q1, o);
        }
        float mu0 = s0 * (1.f / 128.f), mu1 = s1 * (1.f / 128.f);
        float rs0 = rsqrtf(q0 * (1.f / 128.f) - mu0 * mu0 + 1e-5f);
        float rs1 = rsqrtf(q1 * (1.f / 128.f) - mu1 * mu1 + 1e-5f);
        float4 zv;
        zv.x = fmaxf((a00 - mu0) * rs0 * gv.x + bev.x, 0.f);
        zv.y = fmaxf((a10 - mu1) * rs1 * gv.x + bev.x, 0.f);
        zv.z = fmaxf((a01 - mu0) * rs0 * gv.y + bev.y, 0.f);
        zv.w = fmaxf((a11 - mu1) * rs1 * gv.y + bev.y, 0.f);
        *((float4*)&sHZ[wv][256 + 4 * lane]) = zv;
      }

      // GEMM2: col i=lane; 2 nodes
      float bo = b2[lane];
      float o0 = bo, o1 = bo;
#pragma unroll 8
      for (int k = 0; k < 128; k++) {
        float2 zp = *((float2*)&sHZ[wv][256 + k * 2]);
        float wv2 = sW2[k * 64 + lane];
        o0 += zp.x * wv2;
        o1 += zp.y * wv2;
      }

      // residual in registers
      *hcp0 += o0;
      *hcp1 += o1;

      // next-layer pre-LN
      if (l < LAYERS - 1) {
        float lg_ = ln_g[(l + 1) * 64 + lane], lb_ = ln_b[(l + 1) * 64 + lane];
        float h0 = *hcp0, h1 = *hcp1;
        float s0 = h0, q0 = h0 * h0;
        float s1 = h1, q1 = h1 * h1;
#pragma unroll
        for (int o = 32; o; o >>= 1) {
          s0 += __shfl_xor(s0, o); q0 += __shfl_xor(q0, o);
          s1 += __shfl_xor(s1, o); q1 += __shfl_xor(q1, o);
        }
        float mu0 = s0 * (1.f / 64.f), mu1 = s1 * (1.f / 64.f);
        float rs0 = rsqrtf(q0 * (1.f / 64.f) - mu0 * mu0 + 1e-5f);
        float rs1 = rsqrtf(q1 * (1.f / 64.f) - mu1 * mu1 + 1e-5f);
        uout[(g0 << 6) + lane] = fmaxf((h0 - mu0) * rs0 * lg_ + lb_, 0.f);
        uout[(g1i << 6) + lane] = fmaxf((h1 - mu1) * rs1 * lg_ + lb_, 0.f);
      }
    }

    if (l < LAYERS - 1) grid.sync();  // uout visible before next layer reads it
  }

  // ---- final: out = relu(LN(hc, ln_g[0], ln_b[0])) @ W_out + b_out ----
  __syncthreads();  // all waves done with sW1 (layer-27 GEMM1)
  for (int c = wv; c < 16; c += 10) {
    stage16(W_out + c * 256 + lane * 4, sW1 + c * 256);
  }
  {
    float lg_ = ln_g[lane], lb_ = ln_b[lane];
    float v[4] = {hcA0, hcA1, hcB0, hcB1};
#pragma unroll
    for (int q = 0; q < 4; q++) {
      float s = v[q], qq = v[q] * v[q];
#pragma unroll
      for (int o = 32; o; o >>= 1) { s += __shfl_xor(s, o); qq += __shfl_xor(qq, o); }
      float mu = s * (1.f / 64.f);
      float rs = rsqrtf(qq * (1.f / 64.f) - mu * mu + 1e-5f);
      float z = fmaxf((v[q] - mu) * rs * lg_ + lb_, 0.f);
      sHZ[wv][(q >> 1) * 128 + (q & 1) + lane * 2] = z;  // A pairs then B pairs
    }
  }
  __syncthreads();  // drain W_out staging
  {
    float bo = b_out[lane];
    float oA0 = bo, oA1 = bo, oB0 = bo, oB1 = bo;
#pragma unroll 8
    for (int k = 0; k < 64; k++) {
      float2 zpA = *((float2*)&sHZ[wv][k * 2]);
      float2 zpB = *((float2*)&sHZ[wv][128 + k * 2]);
      float wv2 = sW1[k * 64 + lane];
      oA0 += zpA.x * wv2;
      oA1 += zpA.y * wv2;
      oB0 += zpB.x * wv2;
      oB1 += zpB.y * wv2;
    }
    out[(gnA0 << 6) + lane] = oA0;
    out[(gnA1 << 6) + lane] = oA1;
    out[(gnB0 << 6) + lane] = oB0;
    out[(gnB1 << 6) + lane] = oB1;
  }
}

// ---------------- fallback split path (R10/R12, proven) ----------------

__global__ __launch_bounds__(640, 5) void k_layer(
    const float* __restrict__ uin, float* __restrict__ hc, float* __restrict__ uout,
    const float* __restrict__ ea_s, const int* __restrict__ src_s,
    const int* __restrict__ off, const float* __restrict__ tptr, int layer,
    const float* __restrict__ W1, const float* __restrict__ b1,
    const float* __restrict__ g1, const float* __restrict__ be1,
    const float* __restrict__ W2, const float* __restrict__ b2,
    const float* __restrict__ lng, const float* __restrict__ lnb,
    int addRes, int writeU) {
  __shared__ float sW1[64 * 128];
  __shared__ float sW2[128 * 64];
  __shared__ float sHZ[10][256];

  const int tid = threadIdx.x;
  const int lane = tid & 63;
  const int wv = tid >> 6;
  const int nbase = blockIdx.x * NPB;

  for (int c = wv; c < 32; c += 10) {
    stage16(W1 + c * 256 + lane * 4, sW1 + c * 256);
    stage16(W2 + c * 256 + lane * 4, sW2 + c * 256);
  }

  {
    float tv = tptr[layer];
    float hpair[2];
#pragma unroll
    for (int q = 0; q < 2; q++) {
      int gn = __builtin_amdgcn_readfirstlane(nbase + wv * 2 + q);
      hpair[q] = edge_node(gn, uin, ea_s, src_s, off, lane, tv);
    }
    *((float2*)&sHZ[wv][lane * 2]) = make_float2(hpair[0], hpair[1]);
  }
  __syncthreads();

  const int gn0 = nbase + wv * 2;
  const int gn1 = gn0 + 1;

  int j0 = 2 * lane;
  float2 b1v = *((const float2*)&b1[j0]);
  float a00 = b1v.x, a01 = b1v.y, a10 = b1v.x, a11 = b1v.y;
#pragma unroll 8
  for (int k = 0; k < 64; k++) {
    float2 hp = *((float2*)&sHZ[wv][k * 2]);
    float2 wp = *((float2*)&sW1[k * 128 + j0]);
    a00 += hp.x * wp.x; a01 += hp.x * wp.y;
    a10 += hp.y * wp.x; a11 += hp.y * wp.y;
  }

  {
    float2 gv = *((const float2*)&g1[j0]);
    float2 bev = *((const float2*)&be1[j0]);
    float s0 = a00 + a01, q0 = a00 * a00 + a01 * a01;
    float s1 = a10 + a11, q1 = a10 * a10 + a11 * a11;
#pragma unroll
    for (int o = 32; o; o >>= 1) {
      s0 += __shfl_xor(s0, o); q0 += __shfl_xor(q0, o);
      s1 += __shfl_xor(s1, o); q1 += __shfl_xor(q1, o);
    }
    float mu0 = s0 * (1.f / 128.f), mu1 = s1 * (1.f / 128.f);
    float rs0 = rsqrtf(q0 * (1.f / 128.f) - mu0 * mu0 + 1e-5f);
    float rs1 = rsqrtf(q1 * (1.f / 128.f) - mu1 * mu1 + 1e-5f);
    float4 zv;
    zv.x = fmaxf((a00 - mu0) * rs0 * gv.x + bev.x, 0.f);
    zv.y = fmaxf((a10 - mu1) * rs1 * gv.x + bev.x, 0.f);
    zv.z = fmaxf((a01 - mu0) * rs0 * gv.y + bev.y, 0.f);
    zv.w = fmaxf((a11 - mu1) * rs1 * gv.y + bev.y, 0.f);
    *((float4*)&sHZ[wv][4 * lane]) = zv;
  }

  float bo = b2[lane];
  float o0 = bo, o1 = bo;
#pragma unroll 8
  for (int k = 0; k < 128; k++) {
    float2 zp = *((float2*)&sHZ[wv][k * 2]);
    float wv2 = sW2[k * 64 + lane];
    o0 += zp.x * wv2;
    o1 += zp.y * wv2;
  }

  float r0 = addRes ? hc[gn0 * 64 + lane] : 0.f;
  float r1 = addRes ? hc[gn1 * 64 + lane] : 0.f;
  float hcn0 = o0 + r0, hcn1 = o1 + r1;
  hc[gn0 * 64 + lane] = hcn0;
  hc[gn1 * 64 + lane] = hcn1;

  if (writeU) {
    float lg_ = lng[lane], lb_ = lnb[lane];
    float s0 = hcn0, q0 = hcn0 * hcn0;
    float s1 = hcn1, q1 = hcn1 * hcn1;
#pragma unroll
    for (int o = 32; o; o >>= 1) {
      s0 += __shfl_xor(s0, o); q0 += __shfl_xor(q0, o);
      s1 += __shfl_xor(s1, o); q1 += __shfl_xor(q1, o);
    }
    float mu0 = s0 * (1.f / 64.f), mu1 = s1 * (1.f / 64.f);
    float rs0 = rsqrtf(q0 * (1.f / 64.f) - mu0 * mu0 + 1e-5f);
    float rs1 = rsqrtf(q1 * (1.f / 64.f) - mu1 * mu1 + 1e-5f);
    uout[gn0 * 64 + lane] = fmaxf((hcn0 - mu0) * rs0 * lg_ + lb_, 0.f);
    uout[gn1 * 64 + lane] = fmaxf((hcn1 - mu1) * rs1 * lg_ + lb_, 0.f);
  }
}

__global__ __launch_bounds__(256) void k_final(const float* __restrict__ hc, const float* __restrict__ g,
                                               const float* __restrict__ bptr, const float* __restrict__ Wout,
                                               const float* __restrict__ bout, float* __restrict__ out) {
  __shared__ float sW[DIM * DIM];
  int tid = threadIdx.x;
  for (int i = tid; i < 1024; i += 256) ((float4*)sW)[i] = ((const float4*)Wout)[i];
  __syncthreads();
  int lane = tid & 63, w = tid >> 6;
  int n = blockIdx.x * 4 + w;
  if (n >= N_NODES) return;
  float v = hc[n * 64 + lane];
  float s = v, q = v * v;
#pragma unroll
  for (int o = 32; o; o >>= 1) { s += __shfl_xor(s, o); q += __shfl_xor(q, o); }
  float mu = s * (1.f / 64.f);
  float var = q * (1.f / 64.f) - mu * mu;
  float rs = rsqrtf(var + 1e-5f);
  float z = fmaxf((v - mu) * rs * g[lane] + bptr[lane], 0.f);
  float acc = bout[lane];
  for (int k = 0; k < 64; k++) {
    float zk = __shfl(z, k);
    acc += zk * sW[k * 64 + lane];
  }
  out[n * 64 + lane] = acc;
}

// ---------------- host ----------------

extern "C" void kernel_launch(void* const* d_in, const int* in_sizes, int n_in,
                              void* d_out, int out_size, void* d_ws, size_t ws_size,
                              hipStream_t stream) {
  const float* x        = (const float*)d_in[0];
  const float* eattr    = (const float*)d_in[1];
  const int*   src      = (const int*)d_in[2];
  const int*   dst      = (const int*)d_in[3];
  const float* W_node   = (const float*)d_in[4];
  const float* b_node   = (const float*)d_in[5];
  const float* W_edge   = (const float*)d_in[6];
  const float* b_edge   = (const float*)d_in[7];
  const float* t        = (const float*)d_in[8];
  const float* W1       = (const float*)d_in[9];
  const float* b1       = (const float*)d_in[10];
  const float* g1       = (const float*)d_in[11];
  const float* be1      = (const float*)d_in[12];
  const float* W2       = (const float*)d_in[13];
  const float* b2       = (const float*)d_in[14];
  const float* ln_g     = (const float*)d_in[15];
  const float* ln_b     = (const float*)d_in[16];
  const float* W_out    = (const float*)d_in[17];
  const float* b_out    = (const float*)d_in[18];
  float* out = (float*)d_out;

  char* w = (char*)d_ws;
  float* uA      = (float*)w;  w += (size_t)N_NODES * 64 * 4;
  float* uB      = (float*)w;  w += (size_t)N_NODES * 64 * 4;
  float* hcb     = (float*)w;  w += (size_t)N_NODES * 64 * 4;
  int* off       = (int*)w;    w += (size_t)(N_NODES + 1) * 4;
  int* cur       = (int*)w;    w += (size_t)N_NODES * 4;
  int* eids      = (int*)w;    w += (size_t)N_EDGES * 4;
  int* src_s     = (int*)w;    w += (size_t)N_EDGES * 4;
  float4* eattr_s = (float4*)w; w += (size_t)N_EDGES * 16;
  float* ea_s    = (float*)w;  w += (size_t)N_EDGES * 64 * 4;

  hipMemsetAsync(cur, 0, (size_t)N_NODES * 4, stream);
  k_hist<<<(N_EDGES + 255) / 256, 256, 0, stream>>>(dst, cur);
  k_scan<<<1, 256, 0, stream>>>(cur, off);
  k_scatter<<<(N_EDGES + 255) / 256, 256, 0, stream>>>(dst, cur, eids);
  k_sortgather<<<(N_NODES + 3) / 4, 256, 0, stream>>>(off, eids, src, (const float4*)eattr,
                                                      W_edge, b_edge, src_s, eattr_s, ea_s);

  // coop path: 250 blocks (1 block/CU, R6-proven size)
  int maxBlocksPerCU = 0;
  hipError_t qerr = hipOccupancyMaxActiveBlocksPerMultiprocessor(&maxBlocksPerCU, k_all, TPB, 0);
  int dev = 0, nCU = 0;
  hipGetDevice(&dev);
  hipDeviceGetAttribute(&nCU, hipDeviceAttributeMultiprocessorCount, dev);
  bool coop_ok = (qerr == hipSuccess) && ((long)maxBlocksPerCU * (long)nCU >= (long)CBLK);

  hipError_t lerr = hipErrorUnknown;
  if (coop_ok) {
    void* args[] = {
        (void*)&x, (void*)&W_node, (void*)&b_node, (void*)&t,
        (void*)&W1, (void*)&b1, (void*)&g1, (void*)&be1, (void*)&W2, (void*)&b2,
        (void*)&ln_g, (void*)&ln_b, (void*)&W_out, (void*)&b_out,
        (void*)&out, (void*)&ea_s, (void*)&src_s, (void*)&off,
        (void*)&uA, (void*)&uB};
    lerr = hipLaunchCooperativeKernel((const void*)k_all, dim3(CBLK), dim3(TPB), args, 0, stream);
  }
  if (!coop_ok || lerr != hipSuccess) {
    // fallback: proven split path (925 us)
    k_enc<<<(N_NODES * 64 + 255) / 256, 256, 0, stream>>>(x, W_node, b_node, hcb, uA);
    for (int l = 0; l < LAYERS; l++) {
      const float* uin = (l & 1) ? uB : uA;
      float* uo        = (l & 1) ? uA : uB;
      int nxt = (l + 1 < LAYERS) ? (l + 1) : 0;
      k_layer<<<NLB, 640, 0, stream>>>(uin, hcb, uo, ea_s, src_s, off, t, l,
                                       W1 + (size_t)l * DIM * HID, b1 + (size_t)l * HID,
                                       g1 + (size_t)l * HID, be1 + (size_t)l * HID,
                                       W2 + (size_t)l * HID * DIM, b2 + (size_t)l * DIM,
                                       ln_g + (size_t)nxt * DIM, ln_b + (size_t)nxt * DIM,
                                       (l > 0) ? 1 : 0, (l < LAYERS - 1) ? 1 : 0);
    }
    k_final<<<(N_NODES + 3) / 4, 256, 0, stream>>>(hcb, ln_g, ln_b, W_out, b_out, out);
  }
}

// Round 14
// 875.724 us; speedup vs baseline: 1.0585x; 1.0585x over previous
//
#include <hip/hip_runtime.h>

#define N_NODES 10000
#define N_EDGES 160000
#define NUM_FEAT 14
#define EDGE_DIM 4
#define DIM 64
#define HID 128
#define LAYERS 28

#define NPB 20
#define NLB (N_NODES / NPB)  // 500 blocks, exact
#define TPB 640              // 10 waves

// async global->LDS, 16B/lane: gsrc per-lane (base + lane*4 floats), lds_base
// wave-uniform; HW writes lds_base + lane*16.
__device__ __forceinline__ void stage16(const float* gsrc, float* lds_base) {
  __builtin_amdgcn_global_load_lds(
      (const __attribute__((address_space(1))) void*)gsrc,
      (__attribute__((address_space(3))) void*)lds_base, 16, 0, 0);
}

// ---------------- CSR build (prologue) ----------------

__global__ __launch_bounds__(256) void k_hist(const int* __restrict__ dst, int* __restrict__ cur) {
  int e = blockIdx.x * 256 + threadIdx.x;
  if (e < N_EDGES) atomicAdd(&cur[dst[e]], 1);
}

__global__ __launch_bounds__(256) void k_scan(int* __restrict__ cur, int* __restrict__ off) {
  __shared__ int part[256];
  int t = threadIdx.x;
  const int CH = 40;
  int base = t * CH;
  int s = 0;
  for (int i = 0; i < CH; i++) {
    int idx = base + i;
    if (idx < N_NODES) s += cur[idx];
  }
  part[t] = s;
  __syncthreads();
  for (int ofs = 1; ofs < 256; ofs <<= 1) {
    int tmp = (t >= ofs) ? part[t - ofs] : 0;
    __syncthreads();
    part[t] += tmp;
    __syncthreads();
  }
  int run = part[t] - s;
  for (int i = 0; i < CH; i++) {
    int idx = base + i;
    if (idx < N_NODES) {
      int d = cur[idx];
      off[idx] = run;
      cur[idx] = run;
      run += d;
    }
  }
  if (t == 255) off[N_NODES] = part[255];
}

__global__ __launch_bounds__(256) void k_scatter(const int* __restrict__ dst, int* __restrict__ cur,
                                                 int* __restrict__ eids) {
  int e = blockIdx.x * 256 + threadIdx.x;
  if (e < N_EDGES) {
    int p = atomicAdd(&cur[dst[e]], 1);
    eids[p] = e;
  }
}

// wave-per-node bitonic sort by edge id; gather src + eattr into slot order.
// (No 41MB ea table any more -- ea is recomputed in-layer from L2-resident eattr_s.)
__global__ __launch_bounds__(256) void k_sortgather(
    const int* __restrict__ off, const int* __restrict__ eids,
    const int* __restrict__ src, const float4* __restrict__ eattr,
    int* __restrict__ src_s, float4* __restrict__ eattr_s) {
  int node = blockIdx.x * 4 + (threadIdx.x >> 6);
  int lane = threadIdx.x & 63;
  if (node >= N_NODES) return;
  int a = off[node];
  int d = off[node + 1] - a;
  if (d <= 64) {
    int key = (lane < d) ? eids[a + lane] : 0x7fffffff;
#pragma unroll
    for (int k = 2; k <= 64; k <<= 1) {
      for (int j = k >> 1; j > 0; j >>= 1) {
        int p = __shfl_xor(key, j);
        bool dirUp = ((lane & k) == 0);
        bool isLower = ((lane & j) == 0);
        key = ((isLower == dirUp) ? min(key, p) : max(key, p));
      }
    }
    if (lane < d) {
      src_s[a + lane] = src[key];
      eattr_s[a + lane] = eattr[key];
    }
  } else {
    for (int i = lane; i < d; i += 64) {
      int e = eids[a + i];
      int r = 0;
      for (int j = 0; j < d; j++) r += (eids[a + j] < e) ? 1 : 0;
      src_s[a + r] = src[e];
      eattr_s[a + r] = eattr[e];
    }
  }
}

// ---------------- node encoder ----------------

__global__ __launch_bounds__(256) void k_enc(const float* __restrict__ x, const float* __restrict__ Wn,
                                             const float* __restrict__ bn, float* __restrict__ hc,
                                             float* __restrict__ u) {
  int gid = blockIdx.x * 256 + threadIdx.x;
  if (gid >= N_NODES * DIM) return;
  int n = gid >> 6, j = gid & 63;
  float acc = bn[j];
#pragma unroll
  for (int k = 0; k < NUM_FEAT; k++) acc += x[n * NUM_FEAT + k] * Wn[k * DIM + j];
  hc[gid] = acc;
  u[gid] = acc;
}

// per-node edge aggregation: batch-8, max-free softmax, ea recomputed from
// wave-uniform eattr_s (s_load_dwordx4, scalar cache) + 4 FMAs. Only per-lane
// memory op is the L2-resident u-row gather (256B/edge).
__device__ __forceinline__ float edge_node(
    int gn, const float* __restrict__ uin, const float4* __restrict__ eattr_s,
    const int* __restrict__ src_s, const int* __restrict__ off,
    int lane, float tv, float we0, float we1, float we2, float we3, float be) {
  int a = off[gn], d = off[gn + 1] - a;  // scalar (gn wave-uniform)
  float un = uin[(gn << 6) + lane];
  float s0 = 0.f, s1 = 0.f, ac0 = 0.f, ac1 = 0.f;
  int i = 0;
  for (; i + 8 <= d; i += 8) {
    float uv[8], ep[8];
#pragma unroll
    for (int j = 0; j < 8; j++) {
      int sn = src_s[a + i + j];          // s_load (uniform addr)
      uv[j] = uin[(sn << 6) + lane];      // sgpr-base gather (L2-resident)
      float4 ev = eattr_s[a + i + j];     // s_load_dwordx4 (uniform addr)
      ep[j] = be + ev.x * we0 + ev.y * we1 + ev.z * we2 + ev.w * we3;
    }
#pragma unroll
    for (int j = 0; j < 8; j++) {
      float msg = fmaxf(uv[j] + ep[j], 0.f) + 1e-7f;
      float e = __expf(msg * tv);
      if (j & 1) { s1 += e; ac1 = fmaf(e, msg, ac1); }
      else       { s0 += e; ac0 = fmaf(e, msg, ac0); }
    }
  }
  for (; i < d; i++) {
    int sn = src_s[a + i];
    float4 ev = eattr_s[a + i];
    float ep = be + ev.x * we0 + ev.y * we1 + ev.z * we2 + ev.w * we3;
    float msg = fmaxf(uin[(sn << 6) + lane] + ep, 0.f) + 1e-7f;
    float e = __expf(msg * tv);
    s0 += e;
    ac0 = fmaf(e, msg, ac0);
  }
  return (ac0 + ac1) / (s0 + s1 + 1e-16f) + un;
}

// ---------------- fused layer: edge-agg + MLP, one dispatch, one barrier ----------------
// R10-proven structure: 640 threads (10 waves), 20 nodes/block, 500 blocks,
// 74KB LDS -> 2 blocks/CU (~20 waves/CU during edge phase). Wave owns 2 nodes.

__global__ __launch_bounds__(640, 5) void k_layer(
    const float* __restrict__ uin, float* __restrict__ hc, float* __restrict__ uout,
    const float4* __restrict__ eattr_s, const int* __restrict__ src_s,
    const int* __restrict__ off, const float* __restrict__ tptr, int layer,
    const float* __restrict__ W_edge, const float* __restrict__ b_edge,
    const float* __restrict__ W1, const float* __restrict__ b1,
    const float* __restrict__ g1, const float* __restrict__ be1,
    const float* __restrict__ W2, const float* __restrict__ b2,
    const float* __restrict__ lng, const float* __restrict__ lnb,
    int addRes, int writeU) {
  __shared__ float sW1[64 * 128];   // 32KB [k][j]
  __shared__ float sW2[128 * 64];   // 32KB [k][i]
  __shared__ float sHZ[10][256];    // 10KB union: h interleaved [0..128), z [0..256)

  const int tid = threadIdx.x;
  const int lane = tid & 63;
  const int wv = tid >> 6;  // 0..9
  const int nbase = blockIdx.x * NPB;

  // ---- stage weights (fire-and-forget; drained by the barrier below) ----
  for (int c = wv; c < 32; c += 10) {
    stage16(W1 + c * 256 + lane * 4, sW1 + c * 256);
    stage16(W2 + c * 256 + lane * 4, sW2 + c * 256);
  }

  // ---- edge aggregation: 2 nodes per wave, ea recomputed from L2 ----
  {
    float tv = tptr[layer];
    float we0 = W_edge[lane], we1 = W_edge[64 + lane], we2 = W_edge[128 + lane],
          we3 = W_edge[192 + lane];
    float be = b_edge[lane];
    int gn0 = __builtin_amdgcn_readfirstlane(nbase + wv * 2);
    float h0 = edge_node(gn0, uin, eattr_s, src_s, off, lane, tv, we0, we1, we2, we3, be);
    float h1 = edge_node(gn0 + 1, uin, eattr_s, src_s, off, lane, tv, we0, we1, we2, we3, be);
    *((float2*)&sHZ[wv][lane * 2]) = make_float2(h0, h1);
  }
  __syncthreads();  // drains global_load_lds (weights ready); sHZ wave-private

  const int gn0 = nbase + wv * 2;
  const int gn1 = gn0 + 1;

  // ---- GEMM1: cols j0=2*lane, j0+1; 2 nodes ----
  int j0 = 2 * lane;
  float2 b1v = *((const float2*)&b1[j0]);
  float a00 = b1v.x, a01 = b1v.y, a10 = b1v.x, a11 = b1v.y;
#pragma unroll 8
  for (int k = 0; k < 64; k++) {
    float2 hp = *((float2*)&sHZ[wv][k * 2]);
    float2 wp = *((float2*)&sW1[k * 128 + j0]);
    a00 += hp.x * wp.x; a01 += hp.x * wp.y;
    a10 += hp.y * wp.x; a11 += hp.y * wp.y;
  }

  // ---- LN1 (over 128) via shfl; z overwrites sHZ (same wave, dep-ordered) ----
  {
    float2 gv = *((const float2*)&g1[j0]);
    float2 bev = *((const float2*)&be1[j0]);
    float s0 = a00 + a01, q0 = a00 * a00 + a01 * a01;
    float s1 = a10 + a11, q1 = a10 * a10 + a11 * a11;
#pragma unroll
    for (int o = 32; o; o >>= 1) {
      s0 += __shfl_xor(s0, o); q0 += __shfl_xor(q0, o);
      s1 += __shfl_xor(s1, o); q1 += __shfl_xor(q1, o);
    }
    float mu0 = s0 * (1.f / 128.f), mu1 = s1 * (1.f / 128.f);
    float rs0 = rsqrtf(q0 * (1.f / 128.f) - mu0 * mu0 + 1e-5f);
    float rs1 = rsqrtf(q1 * (1.f / 128.f) - mu1 * mu1 + 1e-5f);
    float4 zv;
    zv.x = fmaxf((a00 - mu0) * rs0 * gv.x + bev.x, 0.f);
    zv.y = fmaxf((a10 - mu1) * rs1 * gv.x + bev.x, 0.f);
    zv.z = fmaxf((a01 - mu0) * rs0 * gv.y + bev.y, 0.f);
    zv.w = fmaxf((a11 - mu1) * rs1 * gv.y + bev.y, 0.f);
    *((float4*)&sHZ[wv][4 * lane]) = zv;
  }

  // ---- GEMM2: col i=lane; 2 nodes ----
  float bo = b2[lane];
  float o0 = bo, o1 = bo;
#pragma unroll 8
  for (int k = 0; k < 128; k++) {
    float2 zp = *((float2*)&sHZ[wv][k * 2]);
    float wv2 = sW2[k * 64 + lane];
    o0 += zp.x * wv2;
    o1 += zp.y * wv2;
  }

  // ---- residual + hc write ----
  float r0 = addRes ? hc[gn0 * 64 + lane] : 0.f;
  float r1 = addRes ? hc[gn1 * 64 + lane] : 0.f;
  float hcn0 = o0 + r0, hcn1 = o1 + r1;
  hc[gn0 * 64 + lane] = hcn0;
  hc[gn1 * 64 + lane] = hcn1;

  // ---- next-layer pre-LN: uout = relu(LN(hc)) ----
  if (writeU) {
    float lg_ = lng[lane], lb_ = lnb[lane];
    float s0 = hcn0, q0 = hcn0 * hcn0;
    float s1 = hcn1, q1 = hcn1 * hcn1;
#pragma unroll
    for (int o = 32; o; o >>= 1) {
      s0 += __shfl_xor(s0, o); q0 += __shfl_xor(q0, o);
      s1 += __shfl_xor(s1, o); q1 += __shfl_xor(q1, o);
    }
    float mu0 = s0 * (1.f / 64.f), mu1 = s1 * (1.f / 64.f);
    float rs0 = rsqrtf(q0 * (1.f / 64.f) - mu0 * mu0 + 1e-5f);
    float rs1 = rsqrtf(q1 * (1.f / 64.f) - mu1 * mu1 + 1e-5f);
    uout[gn0 * 64 + lane] = fmaxf((hcn0 - mu0) * rs0 * lg_ + lb_, 0.f);
    uout[gn1 * 64 + lane] = fmaxf((hcn1 - mu1) * rs1 * lg_ + lb_, 0.f);
  }
}

// ---------------- final: out = relu(LN(hc, g0, b0)) @ W_out + b_out ----------------

__global__ __launch_bounds__(256) void k_final(const float* __restrict__ hc, const float* __restrict__ g,
                                               const float* __restrict__ bptr, const float* __restrict__ Wout,
                                               const float* __restrict__ bout, float* __restrict__ out) {
  __shared__ float sW[DIM * DIM];
  int tid = threadIdx.x;
  for (int i = tid; i < 1024; i += 256) ((float4*)sW)[i] = ((const float4*)Wout)[i];
  __syncthreads();
  int lane = tid & 63, w = tid >> 6;
  int n = blockIdx.x * 4 + w;
  if (n >= N_NODES) return;
  float v = hc[n * 64 + lane];
  float s = v, q = v * v;
#pragma unroll
  for (int o = 32; o; o >>= 1) { s += __shfl_xor(s, o); q += __shfl_xor(q, o); }
  float mu = s * (1.f / 64.f);
  float var = q * (1.f / 64.f) - mu * mu;
  float rs = rsqrtf(var + 1e-5f);
  float z = fmaxf((v - mu) * rs * g[lane] + bptr[lane], 0.f);
  float acc = bout[lane];
  for (int k = 0; k < 64; k++) {
    float zk = __shfl(z, k);
    acc += zk * sW[k * 64 + lane];
  }
  out[n * 64 + lane] = acc;
}

// ---------------- host ----------------

extern "C" void kernel_launch(void* const* d_in, const int* in_sizes, int n_in,
                              void* d_out, int out_size, void* d_ws, size_t ws_size,
                              hipStream_t stream) {
  const float* x        = (const float*)d_in[0];
  const float* eattr    = (const float*)d_in[1];
  const int*   src      = (const int*)d_in[2];
  const int*   dst      = (const int*)d_in[3];
  const float* W_node   = (const float*)d_in[4];
  const float* b_node   = (const float*)d_in[5];
  const float* W_edge   = (const float*)d_in[6];
  const float* b_edge   = (const float*)d_in[7];
  const float* t        = (const float*)d_in[8];
  const float* W1       = (const float*)d_in[9];
  const float* b1       = (const float*)d_in[10];
  const float* g1       = (const float*)d_in[11];
  const float* be1      = (const float*)d_in[12];
  const float* W2       = (const float*)d_in[13];
  const float* b2       = (const float*)d_in[14];
  const float* ln_g     = (const float*)d_in[15];
  const float* ln_b     = (const float*)d_in[16];
  const float* W_out    = (const float*)d_in[17];
  const float* b_out    = (const float*)d_in[18];
  float* out = (float*)d_out;

  char* w = (char*)d_ws;
  float* uA      = (float*)w;  w += (size_t)N_NODES * 64 * 4;
  float* uB      = (float*)w;  w += (size_t)N_NODES * 64 * 4;
  float* hcb     = (float*)w;  w += (size_t)N_NODES * 64 * 4;
  int* off       = (int*)w;    w += (size_t)(N_NODES + 1) * 4;
  int* cur       = (int*)w;    w += (size_t)N_NODES * 4;
  int* eids      = (int*)w;    w += (size_t)N_EDGES * 4;
  int* src_s     = (int*)w;    w += (size_t)N_EDGES * 4;
  float4* eattr_s = (float4*)w; w += (size_t)N_EDGES * 16;

  hipMemsetAsync(cur, 0, (size_t)N_NODES * 4, stream);
  k_hist<<<(N_EDGES + 255) / 256, 256, 0, stream>>>(dst, cur);
  k_scan<<<1, 256, 0, stream>>>(cur, off);
  k_scatter<<<(N_EDGES + 255) / 256, 256, 0, stream>>>(dst, cur, eids);
  k_sortgather<<<(N_NODES + 3) / 4, 256, 0, stream>>>(off, eids, src, (const float4*)eattr,
                                                      src_s, eattr_s);

  k_enc<<<(N_NODES * 64 + 255) / 256, 256, 0, stream>>>(x, W_node, b_node, hcb, uA);

  for (int l = 0; l < LAYERS; l++) {
    const float* uin = (l & 1) ? uB : uA;
    float* uo        = (l & 1) ? uA : uB;
    int nxt = (l + 1 < LAYERS) ? (l + 1) : 0;  // unused when writeU=0
    k_layer<<<NLB, TPB, 0, stream>>>(uin, hcb, uo, (const float4*)eattr_s, src_s, off, t, l,
                                     W_edge, b_edge,
                                     W1 + (size_t)l * DIM * HID, b1 + (size_t)l * HID,
                                     g1 + (size_t)l * HID, be1 + (size_t)l * HID,
                                     W2 + (size_t)l * HID * DIM, b2 + (size_t)l * DIM,
                                     ln_g + (size_t)nxt * DIM, ln_b + (size_t)nxt * DIM,
                                     (l > 0) ? 1 : 0, (l < LAYERS - 1) ? 1 : 0);
  }

  k_final<<<(N_NODES + 3) / 4, 256, 0, stream>>>(hcb, ln_g, ln_b, W_out, b_out, out);
}